// Round 19
// baseline (113.804 us; speedup 1.0000x reference)
//
#include <hip/hip_runtime.h>
#include <hip/hip_fp16.h>

#define N_NODES 100000
#define N_EDGES 3200000
#define F_IN    128
#define DIM     16

#define SUP_SH  9
#define NSUP    196                      // ceil(100000/512)
#define SCAP    17920                    // per-super capacity: mean 16384 + 12 sigma
#define CHA     4096
#define NBLKA   ((N_EDGES + CHA - 1) / CHA)   // 782
#define NCAP    96                       // per-node csr capacity (mean 32 + 11 sigma)
#define GROWS   32                       // gemm rows per block (512 thr)
#define NBLKG   (N_NODES / GROWS)        // 3125
#define NAGG    ((N_NODES + 63) / 64)    // agg blocks: 64 nodes per 256-thr block

static inline size_t alignup(size_t x) { return (x + 255) & ~(size_t)255; }

// ---------------------------------------------------------------------------
// zero-init of partA's relative cursors (256 ints; 1 block)
// ---------------------------------------------------------------------------
__global__ void zero_init(int* __restrict__ cursorA) {
    cursorA[threadIdx.x] = 0;
}

// ---------------------------------------------------------------------------
// FUSED partition + GEMM1 with INTERLEAVED block ids: bid%5==0 -> partition
// (782 of 3907), else gemm (3125). Interleave proven r17 (+11us). partA
// internals r13-verbatim (shfl-scan collapses codegen, r12/r14 — frozen).
// ---------------------------------------------------------------------------
__global__ __launch_bounds__(512) void partA_gemm(const int* __restrict__ row,
                                                  const int* __restrict__ col,
                                                  int* __restrict__ cursorA,
                                                  unsigned* __restrict__ stageA,
                                                  const float* __restrict__ x,
                                                  const float* __restrict__ W,
                                                  __half* __restrict__ hu) {
    __shared__ __align__(16) char smem[25600];
    const int t = threadIdx.x;
    const int bid = blockIdx.x;

    if (bid % 5 == 0) {
        // ---------------- partition path (block bid/5 of 782) ----------------
        int* hist   = (int*)smem;                 // 256
        int* lstart = hist + 256;
        int* lcur   = hist + 512;
        int* gbase  = hist + 768;
        int* scanT  = hist + 1024;
        unsigned* stg = (unsigned*)(smem + 5120);             // 16 KB
        unsigned char* stgb = (unsigned char*)(smem + 21504); // 4 KB

        const int e0 = (bid / 5) * CHA;
        const int nv = min(CHA, N_EDGES - e0);
        const int i0 = t * 8;
        const bool act = (i0 < nv);          // nv is always a multiple of 8

        if (t < 256) hist[t] = 0;

        int4 c0, c1, r0, r1;
        if (act) {                           // load 8 edges once, keep in regs
            c0 = *(const int4*)(col + e0 + i0);
            c1 = *(const int4*)(col + e0 + i0 + 4);
            r0 = *(const int4*)(row + e0 + i0);
            r1 = *(const int4*)(row + e0 + i0 + 4);
        }
        __syncthreads();                                     // B1
        if (act) {
            atomicAdd(&hist[(unsigned)c0.x >> SUP_SH], 1);
            atomicAdd(&hist[(unsigned)c0.y >> SUP_SH], 1);
            atomicAdd(&hist[(unsigned)c0.z >> SUP_SH], 1);
            atomicAdd(&hist[(unsigned)c0.w >> SUP_SH], 1);
            atomicAdd(&hist[(unsigned)c1.x >> SUP_SH], 1);
            atomicAdd(&hist[(unsigned)c1.y >> SUP_SH], 1);
            atomicAdd(&hist[(unsigned)c1.z >> SUP_SH], 1);
            atomicAdd(&hist[(unsigned)c1.w >> SUP_SH], 1);
        }
        __syncthreads();                                     // B2
        int v = 0;
        if (t < 256) { v = hist[t]; scanT[t] = v; }
        __syncthreads();
#pragma unroll
        for (int off = 1; off < 256; off <<= 1) {            // proven ladder
            int a = (t >= off && t < 256) ? scanT[t - off] : 0;
            __syncthreads();
            if (t < 256) scanT[t] += a;
            __syncthreads();
        }
        if (t < 256) {
            int ex = scanT[t] - v;
            lstart[t] = ex; lcur[t] = ex;
            if (v) {
                int gb = atomicAdd(&cursorA[t], v);          // relative
                if (gb + v > SCAP) gb = SCAP - v;            // safety clamp
                gbase[t] = t * SCAP + gb;
            }
        }
        __syncthreads();                                     // B3
        if (act) {
            int cc[8] = { c0.x, c0.y, c0.z, c0.w, c1.x, c1.y, c1.z, c1.w };
            int rr[8] = { r0.x, r0.y, r0.z, r0.w, r1.x, r1.y, r1.z, r1.w };
#pragma unroll
            for (int q = 0; q < 8; ++q) {
                int sp = (unsigned)cc[q] >> SUP_SH;
                int p = atomicAdd(&lcur[sp], 1);
                stg[p] = (unsigned)rr[q] | ((unsigned)(cc[q] & 511) << 17);
                stgb[p] = (unsigned char)sp;
            }
        }
        __syncthreads();                                     // B4
        for (int i = t; i < nv; i += 512) {                  // coalesced flush
            int sp = stgb[i];
            stageA[gbase[sp] + (i - lstart[sp])] = stg[i];
        }
    } else {
        // ---------------- gemm path: hu = x @ W1 (unfolded fp16) ----------
        float4* sW4 = (float4*)smem;                         // 8 KB
        float4 (*sX4)[F_IN / 4 + 1] = (float4 (*)[F_IN / 4 + 1])(smem + 8192); // 16.9 KB
        const int gb = bid - bid / 5 - 1;     // gemm block index (0..3124)
        const int base = gb * GROWS;
        sW4[t] = ((const float4*)W)[t];       // 512 float4 = whole W1
#pragma unroll
        for (int i = t; i < GROWS * (F_IN / 4); i += 512) {
            int r = i >> 5, k4 = i & 31;
            sX4[r][k4] = ((const float4*)(x + (size_t)(base + r) * F_IN))[k4];
        }
        __syncthreads();
        const float* sW = (const float*)sW4;
        const int rrow = t >> 4, cj = t & 15;
        const float* xr = (const float*)&sX4[rrow][0];
        float acc = 0.f;
#pragma unroll
        for (int k = 0; k < F_IN; ++k) acc += xr[k] * sW[k * DIM + cj];
        hu[(size_t)(base + rrow) * DIM + cj] = __float2half(acc);
    }
}

// ---------------------------------------------------------------------------
// pass B: permute-scatter + dinv-fold epilogue. ONE 1024-thread block per
// super. csr entries PRE-SCALED (src*8 = half2 index). Epilogue scales
// hu -> hd with dinv computed from the final cursors (degrees).
// ---------------------------------------------------------------------------
__global__ __launch_bounds__(1024) void partB(const unsigned* __restrict__ stageA,
                                              const int* __restrict__ cursorA,
                                              int* __restrict__ nodeCur,
                                              unsigned* __restrict__ csr,
                                              const __half2* __restrict__ hu,
                                              __half2* __restrict__ hd) {
    __shared__ int lcur[512];
    __shared__ float dl[512];
    const int t = threadIdx.x;
    const int sup = blockIdx.x;
    const int nbase = sup << SUP_SH;
    if (t < 512) lcur[t] = (nbase + t) * NCAP;
    __syncthreads();
    const int base = sup * SCAP;
    const int cnt = min(cursorA[sup], SCAP);
    for (int i = t; i < cnt; i += 1024) {
        unsigned v = stageA[base + i];
        int n = (v >> 17) & 511;
        int pos = atomicAdd(&lcur[n], 1);
        if (pos < (nbase + n) * NCAP + NCAP)                 // safety clamp
            csr[pos] = (v & 0x1FFFFu) << 3;  // pre-scaled half2 index
    }
    __syncthreads();
    if (t < 512) {
        int node = nbase + t;
        if (node < N_NODES) {
            int deg = min(lcur[t] - node * NCAP, NCAP);
            nodeCur[node] = deg;
            dl[t] = rsqrtf((float)deg + 1.0f);
        }
    }
    __syncthreads();
    const int nn = min(N_NODES - nbase, 512);
    for (int idx = t; idx < nn * 8; idx += 1024) {           // hd = dinv * hu
        int nl = idx >> 3, f = idx & 7;
        float2 vf = __half22float2(hu[(size_t)(nbase + nl) * 8 + f]);
        float d = dl[nl];
        hd[(size_t)(nbase + nl) * 8 + f] = __floats2half2_rn(vf.x * d, vf.y * d);
    }
}

// ---------------------------------------------------------------------------
// Aggregates: 4 lanes per node (lane q owns features 4q..4q+3 via one 8B
// uint2 gather) -> 16 nodes/wave, per-edge VMEM issue HALVED vs 8-lane form.
// Pairwise __hadd2 (numerically free, r18) + float tree accumulate.
// ---------------------------------------------------------------------------
#define HX(u) (*(const __half2*)&(u).x)
#define HY(u) (*(const __half2*)&(u).y)

__device__ __forceinline__ void node_gather4(const unsigned* __restrict__ csr,
                                             const __half2* __restrict__ h2,
                                             int p, int end, int q2,
                                             float2& a0, float2& a1) {
    for (; p + 15 < end; p += 16) {
        uint4 ea = *(const uint4*)(csr + p);
        uint4 eb = *(const uint4*)(csr + p + 4);
        uint4 ec = *(const uint4*)(csr + p + 8);
        uint4 ed = *(const uint4*)(csr + p + 12);
        uint2 u0 = *(const uint2*)(h2 + ea.x + q2);
        uint2 u1 = *(const uint2*)(h2 + ea.y + q2);
        uint2 u2 = *(const uint2*)(h2 + ea.z + q2);
        uint2 u3 = *(const uint2*)(h2 + ea.w + q2);
        uint2 u4 = *(const uint2*)(h2 + eb.x + q2);
        uint2 u5 = *(const uint2*)(h2 + eb.y + q2);
        uint2 u6 = *(const uint2*)(h2 + eb.z + q2);
        uint2 u7 = *(const uint2*)(h2 + eb.w + q2);
        uint2 u8 = *(const uint2*)(h2 + ec.x + q2);
        uint2 u9 = *(const uint2*)(h2 + ec.y + q2);
        uint2 ua = *(const uint2*)(h2 + ec.z + q2);
        uint2 ub = *(const uint2*)(h2 + ec.w + q2);
        uint2 uc = *(const uint2*)(h2 + ed.x + q2);
        uint2 ud = *(const uint2*)(h2 + ed.y + q2);
        uint2 ue = *(const uint2*)(h2 + ed.z + q2);
        uint2 uf = *(const uint2*)(h2 + ed.w + q2);
        float2 l0 = __half22float2(__hadd2(HX(u0), HX(u1)));
        float2 l1 = __half22float2(__hadd2(HX(u2), HX(u3)));
        float2 l2 = __half22float2(__hadd2(HX(u4), HX(u5)));
        float2 l3 = __half22float2(__hadd2(HX(u6), HX(u7)));
        float2 l4 = __half22float2(__hadd2(HX(u8), HX(u9)));
        float2 l5 = __half22float2(__hadd2(HX(ua), HX(ub)));
        float2 l6 = __half22float2(__hadd2(HX(uc), HX(ud)));
        float2 l7 = __half22float2(__hadd2(HX(ue), HX(uf)));
        a0.x += ((l0.x + l1.x) + (l2.x + l3.x)) + ((l4.x + l5.x) + (l6.x + l7.x));
        a0.y += ((l0.y + l1.y) + (l2.y + l3.y)) + ((l4.y + l5.y) + (l6.y + l7.y));
        float2 h0 = __half22float2(__hadd2(HY(u0), HY(u1)));
        float2 h1 = __half22float2(__hadd2(HY(u2), HY(u3)));
        float2 h3 = __half22float2(__hadd2(HY(u6), HY(u7)));
        float2 h2v = __half22float2(__hadd2(HY(u4), HY(u5)));
        float2 h4 = __half22float2(__hadd2(HY(u8), HY(u9)));
        float2 h5 = __half22float2(__hadd2(HY(ua), HY(ub)));
        float2 h6 = __half22float2(__hadd2(HY(uc), HY(ud)));
        float2 h7 = __half22float2(__hadd2(HY(ue), HY(uf)));
        a1.x += ((h0.x + h1.x) + (h2v.x + h3.x)) + ((h4.x + h5.x) + (h6.x + h7.x));
        a1.y += ((h0.y + h1.y) + (h2v.y + h3.y)) + ((h4.y + h5.y) + (h6.y + h7.y));
    }
    if (p + 7 < end) {
        uint4 ea = *(const uint4*)(csr + p);
        uint4 eb = *(const uint4*)(csr + p + 4);
        uint2 u0 = *(const uint2*)(h2 + ea.x + q2);
        uint2 u1 = *(const uint2*)(h2 + ea.y + q2);
        uint2 u2 = *(const uint2*)(h2 + ea.z + q2);
        uint2 u3 = *(const uint2*)(h2 + ea.w + q2);
        uint2 u4 = *(const uint2*)(h2 + eb.x + q2);
        uint2 u5 = *(const uint2*)(h2 + eb.y + q2);
        uint2 u6 = *(const uint2*)(h2 + eb.z + q2);
        uint2 u7 = *(const uint2*)(h2 + eb.w + q2);
        float2 l0 = __half22float2(__hadd2(HX(u0), HX(u1)));
        float2 l1 = __half22float2(__hadd2(HX(u2), HX(u3)));
        float2 l2 = __half22float2(__hadd2(HX(u4), HX(u5)));
        float2 l3 = __half22float2(__hadd2(HX(u6), HX(u7)));
        a0.x += (l0.x + l1.x) + (l2.x + l3.x);
        a0.y += (l0.y + l1.y) + (l2.y + l3.y);
        float2 h0 = __half22float2(__hadd2(HY(u0), HY(u1)));
        float2 h1 = __half22float2(__hadd2(HY(u2), HY(u3)));
        float2 h2v = __half22float2(__hadd2(HY(u4), HY(u5)));
        float2 h3 = __half22float2(__hadd2(HY(u6), HY(u7)));
        a1.x += (h0.x + h1.x) + (h2v.x + h3.x);
        a1.y += (h0.y + h1.y) + (h2v.y + h3.y);
        p += 8;
    }
    if (p + 3 < end) {
        uint4 e4 = *(const uint4*)(csr + p);
        uint2 u0 = *(const uint2*)(h2 + e4.x + q2);
        uint2 u1 = *(const uint2*)(h2 + e4.y + q2);
        uint2 u2 = *(const uint2*)(h2 + e4.z + q2);
        uint2 u3 = *(const uint2*)(h2 + e4.w + q2);
        float2 l0 = __half22float2(__hadd2(HX(u0), HX(u1)));
        float2 l1 = __half22float2(__hadd2(HX(u2), HX(u3)));
        a0.x += l0.x + l1.x;
        a0.y += l0.y + l1.y;
        float2 h0 = __half22float2(__hadd2(HY(u0), HY(u1)));
        float2 h1 = __half22float2(__hadd2(HY(u2), HY(u3)));
        a1.x += h0.x + h1.x;
        a1.y += h0.y + h1.y;
        p += 4;
    }
    for (; p < end; ++p) {
        uint2 u = *(const uint2*)(h2 + csr[p] + q2);
        float2 v0 = __half22float2(HX(u));
        float2 v1 = __half22float2(HY(u));
        a0.x += v0.x; a0.y += v0.y;
        a1.x += v1.x; a1.y += v1.y;
    }
}

// layer 1: l1 = relu(dinv*(sum + hd[c]) + b1); fused GEMM2 via 4-lane shfl
__global__ __launch_bounds__(256) void agg1(const unsigned* __restrict__ csr,
                                            const int* __restrict__ nodeCur,
                                            const __half2* __restrict__ hd,
                                            const float* __restrict__ b1,
                                            const float* __restrict__ W2,
                                            __half2* __restrict__ hd2) {
    __shared__ float sW2[DIM * DIM];
    __shared__ float sb1[DIM];
    const int t = threadIdx.x;
    sW2[t] = W2[t];
    if (t < DIM) sb1[t] = b1[t];
    __syncthreads();
    const int lane = t & 63, q = lane & 3, q2 = q * 2;
    const int node = blockIdx.x * 64 + ((t >> 6) << 4) + (lane >> 2);
    if (node >= N_NODES) return;
    const int degv = nodeCur[node];
    const float dc = rsqrtf((float)degv + 1.0f);
    const int p0 = node * NCAP;
    float2 a0 = make_float2(0.f, 0.f), a1 = make_float2(0.f, 0.f);
    node_gather4(csr, hd, p0, p0 + degv, q2, a0, a1);
    uint2 su = *(const uint2*)(hd + (size_t)node * 8 + q2);
    float2 sv0 = __half22float2(HX(su));
    float2 sv1 = __half22float2(HY(su));
    float f0 = fmaxf(dc * (a0.x + sv0.x) + sb1[4 * q + 0], 0.f);
    float f1 = fmaxf(dc * (a0.y + sv0.y) + sb1[4 * q + 1], 0.f);
    float f2 = fmaxf(dc * (a1.x + sv1.x) + sb1[4 * q + 2], 0.f);
    float f3 = fmaxf(dc * (a1.y + sv1.y) + sb1[4 * q + 3], 0.f);
    float s0 = 0.f, s1 = 0.f, s2 = 0.f, s3 = 0.f;
    const int gl = lane & 60;                 // 4-lane group base
#pragma unroll
    for (int mq = 0; mq < 4; ++mq) {
        float l0 = __shfl(f0, gl + mq, 64);   // l1[4mq+0]
        float l1v = __shfl(f1, gl + mq, 64);  // l1[4mq+1]
        float l2 = __shfl(f2, gl + mq, 64);   // l1[4mq+2]
        float l3 = __shfl(f3, gl + mq, 64);   // l1[4mq+3]
        const int k = 4 * mq;
        const float* w0 = &sW2[(k + 0) * DIM + 4 * q];
        const float* w1 = &sW2[(k + 1) * DIM + 4 * q];
        const float* w2 = &sW2[(k + 2) * DIM + 4 * q];
        const float* w3 = &sW2[(k + 3) * DIM + 4 * q];
        s0 += l0 * w0[0] + l1v * w1[0] + l2 * w2[0] + l3 * w3[0];
        s1 += l0 * w0[1] + l1v * w1[1] + l2 * w2[1] + l3 * w3[1];
        s2 += l0 * w0[2] + l1v * w1[2] + l2 * w2[2] + l3 * w3[2];
        s3 += l0 * w0[3] + l1v * w1[3] + l2 * w2[3] + l3 * w3[3];
    }
    __half2 o0 = __floats2half2_rn(dc * s0, dc * s1);
    __half2 o1 = __floats2half2_rn(dc * s2, dc * s3);
    uint2 ow;
    ow.x = *(unsigned*)&o0;
    ow.y = *(unsigned*)&o1;
    *(uint2*)(hd2 + (size_t)node * 8 + q2) = ow;
}

// layer 2: out = relu(dinv*(sum + hd2[c]) + b2)   (fp32 out, float4 store)
__global__ __launch_bounds__(256) void agg2(const unsigned* __restrict__ csr,
                                            const int* __restrict__ nodeCur,
                                            const __half2* __restrict__ hd2,
                                            const float* __restrict__ b2,
                                            float4* __restrict__ out4) {
    __shared__ float sb2[DIM];
    const int t = threadIdx.x;
    if (t < DIM) sb2[t] = b2[t];
    __syncthreads();
    const int lane = t & 63, q = lane & 3, q2 = q * 2;
    const int node = blockIdx.x * 64 + ((t >> 6) << 4) + (lane >> 2);
    if (node >= N_NODES) return;
    const int degv = nodeCur[node];
    const float dc = rsqrtf((float)degv + 1.0f);
    const int p0 = node * NCAP;
    float2 a0 = make_float2(0.f, 0.f), a1 = make_float2(0.f, 0.f);
    node_gather4(csr, hd2, p0, p0 + degv, q2, a0, a1);
    uint2 su = *(const uint2*)(hd2 + (size_t)node * 8 + q2);
    float2 sv0 = __half22float2(HX(su));
    float2 sv1 = __half22float2(HY(su));
    float4 o;
    o.x = fmaxf(dc * (a0.x + sv0.x) + sb2[4 * q + 0], 0.f);
    o.y = fmaxf(dc * (a0.y + sv0.y) + sb2[4 * q + 1], 0.f);
    o.z = fmaxf(dc * (a1.x + sv1.x) + sb2[4 * q + 2], 0.f);
    o.w = fmaxf(dc * (a1.y + sv1.y) + sb2[4 * q + 3], 0.f);
    out4[(size_t)node * 4 + q] = o;
}

extern "C" void kernel_launch(void* const* d_in, const int* in_sizes, int n_in,
                              void* d_out, int out_size, void* d_ws, size_t ws_size,
                              hipStream_t stream) {
    const float* x   = (const float*)d_in[0];
    const int*   ei  = (const int*)d_in[1];        // [2, E] flat: row then col
    const float* W1  = (const float*)d_in[2];
    const float* b1  = (const float*)d_in[3];
    const float* W2  = (const float*)d_in[4];
    const float* b2  = (const float*)d_in[5];
    float*       out = (float*)d_out;

    const int* row = ei;
    const int* col = ei + N_EDGES;

    // workspace (~63 MB of ~268 MB)
    char* ws = (char*)d_ws;
    size_t o = 0;
    auto take = [&](size_t bytes) { char* p = ws + o; o = alignup(o + bytes); return p; };
    int*      nodeCur = (int*)     take((size_t)N_NODES * 4);         // degrees
    int*      cursorA = (int*)     take((size_t)256 * 4);             // rel cursors
    unsigned* stageA  = (unsigned*)take((size_t)NSUP * SCAP * 4);     // 14.0 MB
    unsigned* csr     = (unsigned*)take((size_t)N_NODES * NCAP * 4);  // 38.4 MB
    __half*   hu      = (__half*)  take((size_t)N_NODES * DIM * 2);   // 3.2 MB
    __half*   hd      = (__half*)  take((size_t)N_NODES * DIM * 2);   // 3.2 MB
    __half*   hd2     = (__half*)  take((size_t)N_NODES * DIM * 2);   // 3.2 MB

    // preprocessing + GEMM1 co-scheduled (interleaved block ids)
    zero_init<<<1, 256, 0, stream>>>(cursorA);
    partA_gemm<<<NBLKA + NBLKG, 512, 0, stream>>>(row, col, cursorA, stageA,
                                                  x, W1, hu);
    partB<<<NSUP, 1024, 0, stream>>>(stageA, cursorA, nodeCur, csr,
                                     (const __half2*)hu, (__half2*)hd);

    // network
    agg1<<<NAGG, 256, 0, stream>>>(csr, nodeCur, (const __half2*)hd,
                                   b1, W2, (__half2*)hd2);
    agg2<<<NAGG, 256, 0, stream>>>(csr, nodeCur, (const __half2*)hd2,
                                   b2, (float4*)out);
}

// Round 20
// 111.236 us; speedup vs baseline: 1.0231x; 1.0231x over previous
//
#include <hip/hip_runtime.h>
#include <hip/hip_fp16.h>

#define N_NODES 100000
#define N_EDGES 3200000
#define F_IN    128
#define DIM     16

#define SUP_SH  9
#define NSUP    196                      // ceil(100000/512)
#define SCAP    17920                    // per-super capacity: mean 16384 + 12 sigma
#define CHA     8192                     // edges per partition block (r20: 2x)
#define NBLKA   ((N_EDGES + CHA - 1) / CHA)   // 391
#define NCAP    96                       // per-node csr capacity (mean 32 + 11 sigma)
#define GROWS   32                       // gemm rows per block (512 thr)
#define NBLKG   (N_NODES / GROWS)        // 3125
#define RATIO   9                        // interleave: bid%9==0 -> partition

static inline size_t alignup(size_t x) { return (x + 255) & ~(size_t)255; }

// ---------------------------------------------------------------------------
// zero-init of partA's relative cursors (256 ints; 1 block)
// ---------------------------------------------------------------------------
__global__ void zero_init(int* __restrict__ cursorA) {
    cursorA[threadIdx.x] = 0;
}

// ---------------------------------------------------------------------------
// FUSED partition + GEMM1, interleaved block ids (r17: +11us vs serial).
// r20 test: CHA 4096->8192 — half the blocks, half the ladder scans and
// barrier phases; 16 edges/thread in 8 int4 registers (ladder scan FROZEN:
// shfl-scan collapses codegen, r12/r14). LDS 46KB -> 3 blocks/CU (was 4).
// ---------------------------------------------------------------------------
__global__ __launch_bounds__(512) void partA_gemm(const int* __restrict__ row,
                                                  const int* __restrict__ col,
                                                  int* __restrict__ cursorA,
                                                  unsigned* __restrict__ stageA,
                                                  const float* __restrict__ x,
                                                  const float* __restrict__ W,
                                                  __half* __restrict__ hu) {
    __shared__ __align__(16) char smem[46080];
    const int t = threadIdx.x;
    const int bid = blockIdx.x;

    if (bid % RATIO == 0) {
        // ---------------- partition path (block bid/9 of 391) ----------------
        int* hist   = (int*)smem;                 // 256
        int* lstart = hist + 256;
        int* lcur   = hist + 512;
        int* gbase  = hist + 768;
        int* scanT  = hist + 1024;
        unsigned* stg = (unsigned*)(smem + 5120);             // 32 KB
        unsigned char* stgb = (unsigned char*)(smem + 37888); // 8 KB

        const int e0 = (bid / RATIO) * CHA;
        const int nv = min(CHA, N_EDGES - e0);
        const int i0 = t * 16;
        const bool act = (i0 < nv);          // nv is always a multiple of 16

        if (t < 256) hist[t] = 0;

        int4 c0, c1, c2, c3, r0, r1, r2, r3;
        if (act) {                           // load 16 edges once, keep in regs
            c0 = *(const int4*)(col + e0 + i0);
            c1 = *(const int4*)(col + e0 + i0 + 4);
            c2 = *(const int4*)(col + e0 + i0 + 8);
            c3 = *(const int4*)(col + e0 + i0 + 12);
            r0 = *(const int4*)(row + e0 + i0);
            r1 = *(const int4*)(row + e0 + i0 + 4);
            r2 = *(const int4*)(row + e0 + i0 + 8);
            r3 = *(const int4*)(row + e0 + i0 + 12);
        }
        __syncthreads();                                     // B1
        if (act) {
            atomicAdd(&hist[(unsigned)c0.x >> SUP_SH], 1);
            atomicAdd(&hist[(unsigned)c0.y >> SUP_SH], 1);
            atomicAdd(&hist[(unsigned)c0.z >> SUP_SH], 1);
            atomicAdd(&hist[(unsigned)c0.w >> SUP_SH], 1);
            atomicAdd(&hist[(unsigned)c1.x >> SUP_SH], 1);
            atomicAdd(&hist[(unsigned)c1.y >> SUP_SH], 1);
            atomicAdd(&hist[(unsigned)c1.z >> SUP_SH], 1);
            atomicAdd(&hist[(unsigned)c1.w >> SUP_SH], 1);
            atomicAdd(&hist[(unsigned)c2.x >> SUP_SH], 1);
            atomicAdd(&hist[(unsigned)c2.y >> SUP_SH], 1);
            atomicAdd(&hist[(unsigned)c2.z >> SUP_SH], 1);
            atomicAdd(&hist[(unsigned)c2.w >> SUP_SH], 1);
            atomicAdd(&hist[(unsigned)c3.x >> SUP_SH], 1);
            atomicAdd(&hist[(unsigned)c3.y >> SUP_SH], 1);
            atomicAdd(&hist[(unsigned)c3.z >> SUP_SH], 1);
            atomicAdd(&hist[(unsigned)c3.w >> SUP_SH], 1);
        }
        __syncthreads();                                     // B2
        int v = 0;
        if (t < 256) { v = hist[t]; scanT[t] = v; }
        __syncthreads();
#pragma unroll
        for (int off = 1; off < 256; off <<= 1) {            // proven ladder
            int a = (t >= off && t < 256) ? scanT[t - off] : 0;
            __syncthreads();
            if (t < 256) scanT[t] += a;
            __syncthreads();
        }
        if (t < 256) {
            int ex = scanT[t] - v;
            lstart[t] = ex; lcur[t] = ex;
            if (v) {
                int gb = atomicAdd(&cursorA[t], v);          // relative
                if (gb + v > SCAP) gb = SCAP - v;            // safety clamp
                gbase[t] = t * SCAP + gb;
            }
        }
        __syncthreads();                                     // B3
        if (act) {
            int cc[16] = { c0.x, c0.y, c0.z, c0.w, c1.x, c1.y, c1.z, c1.w,
                           c2.x, c2.y, c2.z, c2.w, c3.x, c3.y, c3.z, c3.w };
            int rr[16] = { r0.x, r0.y, r0.z, r0.w, r1.x, r1.y, r1.z, r1.w,
                           r2.x, r2.y, r2.z, r2.w, r3.x, r3.y, r3.z, r3.w };
#pragma unroll
            for (int q = 0; q < 16; ++q) {
                int sp = (unsigned)cc[q] >> SUP_SH;
                int p = atomicAdd(&lcur[sp], 1);
                stg[p] = (unsigned)rr[q] | ((unsigned)(cc[q] & 511) << 17);
                stgb[p] = (unsigned char)sp;
            }
        }
        __syncthreads();                                     // B4
        for (int i = t; i < nv; i += 512) {                  // coalesced flush
            int sp = stgb[i];
            stageA[gbase[sp] + (i - lstart[sp])] = stg[i];
        }
    } else {
        // ---------------- gemm path: hu = x @ W1 (unfolded fp16) ----------
        float4* sW4 = (float4*)smem;                         // 8 KB
        float4 (*sX4)[F_IN / 4 + 1] = (float4 (*)[F_IN / 4 + 1])(smem + 8192); // 16.9 KB
        const int gb = bid - bid / RATIO - 1; // gemm block index (0..3124)
        const int base = gb * GROWS;
        sW4[t] = ((const float4*)W)[t];       // 512 float4 = whole W1
#pragma unroll
        for (int i = t; i < GROWS * (F_IN / 4); i += 512) {
            int r = i >> 5, k4 = i & 31;
            sX4[r][k4] = ((const float4*)(x + (size_t)(base + r) * F_IN))[k4];
        }
        __syncthreads();
        const float* sW = (const float*)sW4;
        const int rrow = t >> 4, cj = t & 15;
        const float* xr = (const float*)&sX4[rrow][0];
        float acc = 0.f;
#pragma unroll
        for (int k = 0; k < F_IN; ++k) acc += xr[k] * sW[k * DIM + cj];
        hu[(size_t)(base + rrow) * DIM + cj] = __float2half(acc);
    }
}

// ---------------------------------------------------------------------------
// pass B: permute-scatter + dinv-fold epilogue. ONE 1024-thread block per
// super. csr entries PRE-SCALED (src*8 = half2 index). Epilogue scales
// hu -> hd with dinv computed from the final cursors (degrees).
// ---------------------------------------------------------------------------
__global__ __launch_bounds__(1024) void partB(const unsigned* __restrict__ stageA,
                                              const int* __restrict__ cursorA,
                                              int* __restrict__ nodeCur,
                                              unsigned* __restrict__ csr,
                                              const __half2* __restrict__ hu,
                                              __half2* __restrict__ hd) {
    __shared__ int lcur[512];
    __shared__ float dl[512];
    const int t = threadIdx.x;
    const int sup = blockIdx.x;
    const int nbase = sup << SUP_SH;
    if (t < 512) lcur[t] = (nbase + t) * NCAP;
    __syncthreads();
    const int base = sup * SCAP;
    const int cnt = min(cursorA[sup], SCAP);
    for (int i = t; i < cnt; i += 1024) {
        unsigned v = stageA[base + i];
        int n = (v >> 17) & 511;
        int pos = atomicAdd(&lcur[n], 1);
        if (pos < (nbase + n) * NCAP + NCAP)                 // safety clamp
            csr[pos] = (v & 0x1FFFFu) << 3;  // pre-scaled half2 index
    }
    __syncthreads();
    if (t < 512) {
        int node = nbase + t;
        if (node < N_NODES) {
            int deg = min(lcur[t] - node * NCAP, NCAP);
            nodeCur[node] = deg;
            dl[t] = rsqrtf((float)deg + 1.0f);
        }
    }
    __syncthreads();
    const int nn = min(N_NODES - nbase, 512);
    for (int idx = t; idx < nn * 8; idx += 1024) {           // hd = dinv * hu
        int nl = idx >> 3, f = idx & 7;
        float2 vf = __half22float2(hu[(size_t)(nbase + nl) * 8 + f]);
        float d = dl[nl];
        hd[(size_t)(nbase + nl) * 8 + f] = __floats2half2_rn(vf.x * d, vf.y * d);
    }
}

// ---------------------------------------------------------------------------
// Aggregates (r18 form — both r18 VALU-cut and r19 VMEM-cut probes were
// null/negative; this is the proven best): 8 lanes per node, pairwise
// __hadd2, 16-edge-deep unroll, pre-scaled csr indices.
// ---------------------------------------------------------------------------
__device__ __forceinline__ void node_gather(const unsigned* __restrict__ csr,
                                            const __half2* __restrict__ h2,
                                            int p, int end, int f,
                                            float& ax, float& ay) {
    for (; p + 15 < end; p += 16) {
        uint4 ea = *(const uint4*)(csr + p);
        uint4 eb = *(const uint4*)(csr + p + 4);
        uint4 ec = *(const uint4*)(csr + p + 8);
        uint4 ed = *(const uint4*)(csr + p + 12);
        __half2 g0 = h2[ea.x + f], g1 = h2[ea.y + f];
        __half2 g2 = h2[ea.z + f], g3 = h2[ea.w + f];
        __half2 g4 = h2[eb.x + f], g5 = h2[eb.y + f];
        __half2 g6 = h2[eb.z + f], g7 = h2[eb.w + f];
        __half2 g8 = h2[ec.x + f], g9 = h2[ec.y + f];
        __half2 ga = h2[ec.z + f], gb = h2[ec.w + f];
        __half2 gc = h2[ed.x + f], gd = h2[ed.y + f];
        __half2 ge = h2[ed.z + f], gf = h2[ed.w + f];
        float2 t0 = __half22float2(__hadd2(g0, g1));
        float2 t1 = __half22float2(__hadd2(g2, g3));
        float2 t2 = __half22float2(__hadd2(g4, g5));
        float2 t3 = __half22float2(__hadd2(g6, g7));
        float2 t4 = __half22float2(__hadd2(g8, g9));
        float2 t5 = __half22float2(__hadd2(ga, gb));
        float2 t6 = __half22float2(__hadd2(gc, gd));
        float2 t7 = __half22float2(__hadd2(ge, gf));
        ax += ((t0.x + t1.x) + (t2.x + t3.x)) + ((t4.x + t5.x) + (t6.x + t7.x));
        ay += ((t0.y + t1.y) + (t2.y + t3.y)) + ((t4.y + t5.y) + (t6.y + t7.y));
    }
    if (p + 7 < end) {
        uint4 ea = *(const uint4*)(csr + p);
        uint4 eb = *(const uint4*)(csr + p + 4);
        __half2 g0 = h2[ea.x + f], g1 = h2[ea.y + f];
        __half2 g2 = h2[ea.z + f], g3 = h2[ea.w + f];
        __half2 g4 = h2[eb.x + f], g5 = h2[eb.y + f];
        __half2 g6 = h2[eb.z + f], g7 = h2[eb.w + f];
        float2 t0 = __half22float2(__hadd2(g0, g1));
        float2 t1 = __half22float2(__hadd2(g2, g3));
        float2 t2 = __half22float2(__hadd2(g4, g5));
        float2 t3 = __half22float2(__hadd2(g6, g7));
        ax += (t0.x + t1.x) + (t2.x + t3.x);
        ay += (t0.y + t1.y) + (t2.y + t3.y);
        p += 8;
    }
    if (p + 3 < end) {
        uint4 e4 = *(const uint4*)(csr + p);
        __half2 g0 = h2[e4.x + f], g1 = h2[e4.y + f];
        __half2 g2 = h2[e4.z + f], g3 = h2[e4.w + f];
        float2 t0 = __half22float2(__hadd2(g0, g1));
        float2 t1 = __half22float2(__hadd2(g2, g3));
        ax += t0.x + t1.x;
        ay += t0.y + t1.y;
        p += 4;
    }
    for (; p < end; ++p) {
        float2 v = __half22float2(h2[csr[p] + f]);
        ax += v.x; ay += v.y;
    }
}

// layer 1: l1 = relu(dinv*(sum + hd[c]) + b1); fused GEMM2 via group shfl
__global__ __launch_bounds__(256) void agg1(const unsigned* __restrict__ csr,
                                            const int* __restrict__ nodeCur,
                                            const __half2* __restrict__ hd,
                                            const float* __restrict__ b1,
                                            const float* __restrict__ W2,
                                            __half2* __restrict__ hd2) {
    __shared__ float sW2[DIM * DIM];
    __shared__ float sb1[DIM];
    const int t = threadIdx.x;
    sW2[t] = W2[t];
    if (t < DIM) sb1[t] = b1[t];
    __syncthreads();
    const int lane = t & 63, f = lane & 7;
    const int node = blockIdx.x * 32 + ((t >> 6) << 3) + (lane >> 3);  // grid exact
    const int degv = nodeCur[node];
    const float dc = rsqrtf((float)degv + 1.0f);
    const int p0 = node * NCAP;
    float ax = 0.f, ay = 0.f;
    node_gather(csr, hd, p0, p0 + degv, f, ax, ay);
    float2 sv = __half22float2(hd[(size_t)node * 8 + f]);
    float fx = dc * (ax + sv.x) + sb1[2 * f];
    float fy = dc * (ay + sv.y) + sb1[2 * f + 1];
    fx = fmaxf(fx, 0.f); fy = fmaxf(fy, 0.f);
    float sx = 0.f, sy = 0.f;
    const int gl = lane & 56;                 // group base lane
#pragma unroll
    for (int mq = 0; mq < 8; ++mq) {
        float lo = __shfl(fx, gl + mq, 64);   // l1[2mq]
        float hi = __shfl(fy, gl + mq, 64);   // l1[2mq+1]
        sx += lo * sW2[(2 * mq) * DIM + 2 * f]     + hi * sW2[(2 * mq + 1) * DIM + 2 * f];
        sy += lo * sW2[(2 * mq) * DIM + 2 * f + 1] + hi * sW2[(2 * mq + 1) * DIM + 2 * f + 1];
    }
    hd2[(size_t)node * 8 + f] = __floats2half2_rn(dc * sx, dc * sy);
}

// layer 2: out = relu(dinv*(sum + hd2[c]) + b2)   (fp32 out)
__global__ __launch_bounds__(256) void agg2(const unsigned* __restrict__ csr,
                                            const int* __restrict__ nodeCur,
                                            const __half2* __restrict__ hd2,
                                            const float* __restrict__ b2,
                                            float2* __restrict__ out2) {
    __shared__ float sb2[DIM];
    const int t = threadIdx.x;
    if (t < DIM) sb2[t] = b2[t];
    __syncthreads();
    const int lane = t & 63, f = lane & 7;
    const int node = blockIdx.x * 32 + ((t >> 6) << 3) + (lane >> 3);
    const int degv = nodeCur[node];
    const float dc = rsqrtf((float)degv + 1.0f);
    const int p0 = node * NCAP;
    float ax = 0.f, ay = 0.f;
    node_gather(csr, hd2, p0, p0 + degv, f, ax, ay);
    float2 sv = __half22float2(hd2[(size_t)node * 8 + f]);
    float fx = dc * (ax + sv.x) + sb2[2 * f];
    float fy = dc * (ay + sv.y) + sb2[2 * f + 1];
    out2[(size_t)node * 8 + f] = make_float2(fmaxf(fx, 0.f), fmaxf(fy, 0.f));
}

extern "C" void kernel_launch(void* const* d_in, const int* in_sizes, int n_in,
                              void* d_out, int out_size, void* d_ws, size_t ws_size,
                              hipStream_t stream) {
    const float* x   = (const float*)d_in[0];
    const int*   ei  = (const int*)d_in[1];        // [2, E] flat: row then col
    const float* W1  = (const float*)d_in[2];
    const float* b1  = (const float*)d_in[3];
    const float* W2  = (const float*)d_in[4];
    const float* b2  = (const float*)d_in[5];
    float*       out = (float*)d_out;

    const int* row = ei;
    const int* col = ei + N_EDGES;

    // workspace (~63 MB of ~268 MB)
    char* ws = (char*)d_ws;
    size_t o = 0;
    auto take = [&](size_t bytes) { char* p = ws + o; o = alignup(o + bytes); return p; };
    int*      nodeCur = (int*)     take((size_t)N_NODES * 4);         // degrees
    int*      cursorA = (int*)     take((size_t)256 * 4);             // rel cursors
    unsigned* stageA  = (unsigned*)take((size_t)NSUP * SCAP * 4);     // 14.0 MB
    unsigned* csr     = (unsigned*)take((size_t)N_NODES * NCAP * 4);  // 38.4 MB
    __half*   hu      = (__half*)  take((size_t)N_NODES * DIM * 2);   // 3.2 MB
    __half*   hd      = (__half*)  take((size_t)N_NODES * DIM * 2);   // 3.2 MB
    __half*   hd2     = (__half*)  take((size_t)N_NODES * DIM * 2);   // 3.2 MB

    // preprocessing + GEMM1 co-scheduled (interleaved block ids)
    zero_init<<<1, 256, 0, stream>>>(cursorA);
    partA_gemm<<<NBLKA + NBLKG, 512, 0, stream>>>(row, col, cursorA, stageA,
                                                  x, W1, hu);
    partB<<<NSUP, 1024, 0, stream>>>(stageA, cursorA, nodeCur, csr,
                                     (const __half2*)hu, (__half2*)hd);

    // network
    agg1<<<N_NODES / 32, 256, 0, stream>>>(csr, nodeCur, (const __half2*)hd,
                                           b1, W2, (__half2*)hd2);
    agg2<<<N_NODES / 32, 256, 0, stream>>>(csr, nodeCur, (const __half2*)hd2,
                                           b2, (float2*)out);
}